// Round 6
// baseline (429.557 us; speedup 1.0000x reference)
//
#include <hip/hip_runtime.h>
#include <hip/hip_bf16.h>

#define L_DIM 32
#define N_DIM 1024
#define D_DIM 768
#define K_DIM 16
#define I_DIM 64
#define O_DIM 64
#define EPSF 1e-8f

typedef unsigned short u16;

__device__ __forceinline__ float bf2f(u16 v) {
    union { unsigned int u; float f; } x; x.u = ((unsigned int)v) << 16; return x.f;
}
// dtype-agnostic scalar load: bf=1 -> buffer is bf16, else f32
__device__ __forceinline__ float ldsel(const void* p, size_t i, int bf) {
    return bf ? bf2f(((const u16*)p)[i]) : ((const float*)p)[i];
}

// ---------------------------------------------------------------------------
// Detection: is the x buffer f32 (flag 0) or bf16 (flag 1)?
// ---------------------------------------------------------------------------
__global__ void detect_kernel(const void* __restrict__ x, int* __restrict__ flag) {
    if (threadIdx.x == 0 && blockIdx.x == 0) {
        const float* xf = (const float*)x;
        int good = 0;
        for (int i = 0; i < 128; i++) {
            float v = fabsf(xf[i]);
            if (v > 1e-4f && v < 100.f) good++;
        }
        flag[0] = (good >= 96) ? 0 : 1;
    }
}

// ---------------------------------------------------------------------------
// Kernel A: mu[l,nl,i] = gelu(x[n,l,:]·Wcap[l,:,i] + Bcap[l,i])  (f32, chunk-local)
//           fa[l,nl]   = sigmoid(x[n,l,:]·Wscore[l,:] + Bscore[l]) * mask[n,l]
// grid (nchunk/64, 32), block 256.
// ---------------------------------------------------------------------------
__global__ __launch_bounds__(256) void kernelA(
    const void* __restrict__ x, const void* __restrict__ mask,
    const void* __restrict__ Wscore, const void* __restrict__ Bscore,
    const void* __restrict__ Wcap, const void* __restrict__ Bcap,
    const int* __restrict__ flag,
    float* __restrict__ mu_out, float* __restrict__ fa_out,
    int nbase, int nchunk)
{
    const int bf = flag[0];
    const int l   = blockIdx.y;
    const int n0l = blockIdx.x * 64;          // chunk-local
    const int t  = threadIdx.x;
    const int lane = t & 63;
    const int wv   = t >> 6;

    __shared__ float xs[64][65];
    __shared__ float ws[64][64];
    __shared__ float wsc[64];
    __shared__ float ared[4][64];

    const int tn = (t >> 4) << 2;
    const int ti = (t & 15) << 2;

    float acc[4][4];
    #pragma unroll
    for (int a = 0; a < 4; a++)
        #pragma unroll
        for (int b = 0; b < 4; b++) acc[a][b] = 0.f;
    float apart = 0.f;

    for (int d0 = 0; d0 < D_DIM; d0 += 64) {
        __syncthreads();
        if (bf) {
            const u16* xb = (const u16*)x;
            const u16* wb = (const u16*)Wcap;
            #pragma unroll
            for (int p = 0; p < 16; p++) {
                int n = wv + (p << 2);
                xs[n][lane] = bf2f(xb[((size_t)(nbase + n0l + n) * L_DIM + l) * D_DIM + d0 + lane]);
            }
            #pragma unroll
            for (int p = 0; p < 16; p++) {
                int dd = wv + (p << 2);
                ws[dd][lane] = bf2f(wb[((size_t)l * D_DIM + d0 + dd) * I_DIM + lane]);
            }
        } else {
            const float* xf = (const float*)x;
            const float* wf = (const float*)Wcap;
            #pragma unroll
            for (int p = 0; p < 16; p++) {
                int n = wv + (p << 2);
                xs[n][lane] = xf[((size_t)(nbase + n0l + n) * L_DIM + l) * D_DIM + d0 + lane];
            }
            #pragma unroll
            for (int p = 0; p < 16; p++) {
                int dd = wv + (p << 2);
                ws[dd][lane] = wf[((size_t)l * D_DIM + d0 + dd) * I_DIM + lane];
            }
        }
        if (t < 64) wsc[t] = ldsel(Wscore, (size_t)l * D_DIM + d0 + t, bf);
        __syncthreads();

        {   // a_in partial: wave wv covers dd in [wv*16, wv*16+16), lane over n
            float s = 0.f;
            #pragma unroll
            for (int j = 0; j < 16; j++) {
                int dd = (wv << 4) + j;
                s += xs[lane][dd] * wsc[dd];
            }
            apart += s;
        }
        #pragma unroll
        for (int dd = 0; dd < 64; dd++) {
            float xv[4];
            #pragma unroll
            for (int a = 0; a < 4; a++) xv[a] = xs[tn + a][dd];
            float4 w4 = *(const float4*)&ws[dd][ti];
            const float wb4[4] = {w4.x, w4.y, w4.z, w4.w};
            #pragma unroll
            for (int a = 0; a < 4; a++)
                #pragma unroll
                for (int b = 0; b < 4; b++) acc[a][b] += xv[a] * wb4[b];
        }
    }

    ared[wv][lane] = apart;
    __syncthreads();
    if (t < 64) {
        float a = ared[0][t] + ared[1][t] + ared[2][t] + ared[3][t] + ldsel(Bscore, l, bf);
        float sig = 1.f / (1.f + expf(-a));
        float m = ldsel(mask, (size_t)(nbase + n0l + t) * L_DIM + l, bf);
        fa_out[(size_t)l * nchunk + n0l + t] = sig * m;
    }

    #pragma unroll
    for (int a = 0; a < 4; a++) {
        float4 o;
        float* op = (float*)&o;
        #pragma unroll
        for (int b = 0; b < 4; b++) {
            float v = acc[a][b] + ldsel(Bcap, l * I_DIM + ti + b, bf);
            op[b] = 0.5f * v * (1.f + erff(v * 0.70710678118f));   // exact gelu
        }
        *(float4*)&mu_out[((size_t)l * nchunk + n0l + tn + a) * I_DIM + ti] = o;
    }
}

// ---------------------------------------------------------------------------
// Kernel B: V[l,k,nl,o] = mu[l,nl,:]·Wvote[l,k,:,o] + Bvote[l,k,o]  (f32!)
// grid (nchunk/64, 16, 32), block 256.
// ---------------------------------------------------------------------------
__global__ __launch_bounds__(256) void kernelB(
    const float* __restrict__ mu_in, const void* __restrict__ Wvote,
    const void* __restrict__ Bvote, const int* __restrict__ flag,
    float* __restrict__ V, int nchunk)
{
    const int bf = flag[0];
    const int l   = blockIdx.z;
    const int k   = blockIdx.y;
    const int n0l = blockIdx.x * 64;
    const int t  = threadIdx.x;
    const int lane = t & 63;
    const int wv   = t >> 6;

    __shared__ float mus[64][65];
    __shared__ float wvs[64][64];

    #pragma unroll
    for (int p = 0; p < 16; p++) {
        int n = wv + (p << 2);
        mus[n][lane] = mu_in[((size_t)l * nchunk + n0l + n) * I_DIM + lane];
    }
    if (bf) {
        const u16* wb = (const u16*)Wvote;
        #pragma unroll
        for (int p = 0; p < 16; p++) {
            int i = wv + (p << 2);
            wvs[i][lane] = bf2f(wb[(((size_t)l * K_DIM + k) * I_DIM + i) * O_DIM + lane]);
        }
    } else {
        const float* wf = (const float*)Wvote;
        #pragma unroll
        for (int p = 0; p < 16; p++) {
            int i = wv + (p << 2);
            wvs[i][lane] = wf[(((size_t)l * K_DIM + k) * I_DIM + i) * O_DIM + lane];
        }
    }
    __syncthreads();

    const int tn = (t >> 4) << 2;
    const int to = (t & 15) << 2;

    float bv[4];
    #pragma unroll
    for (int b = 0; b < 4; b++)
        bv[b] = ldsel(Bvote, ((size_t)l * K_DIM + k) * O_DIM + to + b, bf);

    float acc[4][4];
    #pragma unroll
    for (int a = 0; a < 4; a++)
        #pragma unroll
        for (int b = 0; b < 4; b++) acc[a][b] = 0.f;

    #pragma unroll
    for (int i = 0; i < 64; i++) {
        float m4[4];
        #pragma unroll
        for (int a = 0; a < 4; a++) m4[a] = mus[tn + a][i];
        float4 w4 = *(const float4*)&wvs[i][to];
        const float wb4[4] = {w4.x, w4.y, w4.z, w4.w};
        #pragma unroll
        for (int a = 0; a < 4; a++)
            #pragma unroll
            for (int b = 0; b < 4; b++) acc[a][b] += m4[a] * wb4[b];
    }

    #pragma unroll
    for (int a = 0; a < 4; a++) {
        float4 o;
        o.x = acc[a][0] + bv[0];
        o.y = acc[a][1] + bv[1];
        o.z = acc[a][2] + bv[2];
        o.w = acc[a][3] + bv[3];
        *(float4*)&V[(((size_t)l * K_DIM + k) * nchunk + n0l + tn + a) * O_DIM + to] = o;
    }
}

// ---------------------------------------------------------------------------
// Kernel C: EM routing, one block per chunk-local n. Thread t owns k = t/16,
// o in [og, og+4); V[l,k,og..] (f32) in registers. o-sums via 16-lane
// shfl_xor; k-softmax via LDS.  Output f32: a at [0,16K), mu after.
// ---------------------------------------------------------------------------
__global__ __launch_bounds__(256) void kernelC(
    const float* __restrict__ V, const float* __restrict__ fa_in,
    const void* __restrict__ beta_use, const void* __restrict__ beta_ign,
    const int* __restrict__ iters_p, const int* __restrict__ flag,
    float* __restrict__ out, int nbase, int nchunk)
{
    const int bf = flag[0];
    const int nl = blockIdx.x;
    const int ng = nbase + nl;
    const int t  = threadIdx.x;
    const int k  = t >> 4;
    const int og = (t & 15) << 2;
    int iters = iters_p[0];
    if (iters < 0 || iters > 16) iters = 3;   // guard; deterministic

    __shared__ float fa_s[32];
    __shared__ float bu_s[32];
    __shared__ float R_s[32][17];
    __shared__ float sc_s[32][17];

    if (t < 32) {
        fa_s[t] = fa_in[(size_t)t * nchunk + nl];
        bu_s[t] = ldsel(beta_use, t, bf);
    }
    for (int idx = t; idx < 512; idx += 256)
        R_s[idx >> 4][idx & 15] = 1.f / 16.f;
    const float bi_k = ldsel(beta_ign, k, bf);

    float Vr[32][4];
    #pragma unroll
    for (int l = 0; l < 32; l++) {
        float4 v = *(const float4*)&V[(((size_t)l * K_DIM + k) * nchunk + nl) * O_DIM + og];
        Vr[l][0] = v.x; Vr[l][1] = v.y; Vr[l][2] = v.z; Vr[l][3] = v.w;
    }
    __syncthreads();

    float mu_r[4] = {0.f, 0.f, 0.f, 0.f};
    float var_r[4] = {0.f, 0.f, 0.f, 0.f};
    float a_r = 0.f;

    for (int it = 0; it < iters; it++) {
        if (it > 0) {
            float inv2v[4], lvp = 0.f;
            #pragma unroll
            for (int j = 0; j < 4; j++) {
                inv2v[j] = 1.f / (2.f * var_r[j] + EPSF);
                lvp += logf(var_r[j] + EPSF);
            }
            lvp += __shfl_xor(lvp, 1, 64);
            lvp += __shfl_xor(lvp, 2, 64);
            lvp += __shfl_xor(lvp, 4, 64);
            lvp += __shfl_xor(lvp, 8, 64);
            float ls = fminf(a_r, 0.f) - log1pf(expf(-fabsf(a_r)));  // log_sigmoid
            const float cst = ls - 1.f - 1.57079632679f - 0.5f * lvp;
            #pragma unroll
            for (int l = 0; l < 32; l++) {
                float s = 0.f;
                #pragma unroll
                for (int j = 0; j < 4; j++) {
                    float d = Vr[l][j] - mu_r[j];
                    s += d * d * inv2v[j];
                }
                s = -s;
                s += __shfl_xor(s, 1, 64);
                s += __shfl_xor(s, 2, 64);
                s += __shfl_xor(s, 4, 64);
                s += __shfl_xor(s, 8, 64);
                if ((t & 15) == 0) sc_s[l][k] = s + cst;
            }
            __syncthreads();
            if (t < 32) {                 // softmax over k, row l = t
                const int l = t;
                float m = -3.4e38f;
                #pragma unroll
                for (int kk = 0; kk < 16; kk++) m = fmaxf(m, sc_s[l][kk]);
                float e[16]; float sum = 0.f;
                #pragma unroll
                for (int kk = 0; kk < 16; kk++) { e[kk] = expf(sc_s[l][kk] - m); sum += e[kk]; }
                float inv = 1.f / sum;
                #pragma unroll
                for (int kk = 0; kk < 16; kk++) R_s[l][kk] = e[kk] * inv;
            }
            __syncthreads();
        }
        float denom = EPSF, a_acc = 0.f;
        float mu_a[4] = {0.f, 0.f, 0.f, 0.f};
        #pragma unroll
        for (int l = 0; l < 32; l++) {
            float Du = fa_s[l] * R_s[l][k];
            denom += Du;
            #pragma unroll
            for (int j = 0; j < 4; j++) mu_a[j] += Du * Vr[l][j];
            a_acc += bu_s[l] * Du - bi_k * (fa_s[l] - Du);
        }
        float invd = 1.f / denom;
        #pragma unroll
        for (int j = 0; j < 4; j++) mu_r[j] = mu_a[j] * invd;
        a_r = a_acc;
        float var_a[4] = {0.f, 0.f, 0.f, 0.f};
        #pragma unroll
        for (int l = 0; l < 32; l++) {
            float Du = fa_s[l] * R_s[l][k];
            #pragma unroll
            for (int j = 0; j < 4; j++) {
                float d = Vr[l][j] - mu_r[j];
                var_a[j] += Du * d * d;
            }
        }
        #pragma unroll
        for (int j = 0; j < 4; j++) var_r[j] = var_a[j] * invd;
    }

    // f32 output: a_fin [n][k] then mu_fin [n][k][o]
    if ((t & 15) == 0) out[(size_t)ng * K_DIM + k] = a_r;
    float4 o4;
    o4.x = mu_r[0]; o4.y = mu_r[1]; o4.z = mu_r[2]; o4.w = mu_r[3];
    *(float4*)&out[(size_t)N_DIM * K_DIM + ((size_t)ng * K_DIM + k) * O_DIM + og] = o4;
}

extern "C" void kernel_launch(void* const* d_in, const int* in_sizes, int n_in,
                              void* d_out, int out_size, void* d_ws, size_t ws_size,
                              hipStream_t stream) {
    (void)out_size;
    // identify inputs by element count (first-fit); falls back to identity
    static const int EXP[11] = {25165824, 32768, 24576, 32, 1572864, 64,
                                2097152, 65536, 32, 16, 1};
    int mapi[11];
    bool used[64] = {false};
    for (int s = 0; s < 11; s++) {
        mapi[s] = (s < n_in) ? s : 0;
        for (int j = 0; j < n_in && j < 64; j++) {
            if (!used[j] && in_sizes[j] == EXP[s]) { mapi[s] = j; used[j] = true; break; }
        }
    }
    const void* x        = d_in[mapi[0]];
    const void* mask     = d_in[mapi[1]];
    const void* Wscore   = d_in[mapi[2]];
    const void* Bscore   = d_in[mapi[3]];
    const void* Wcap     = d_in[mapi[4]];
    const void* Bcap     = d_in[mapi[5]];
    const void* Wvote    = d_in[mapi[6]];
    const void* Bvote    = d_in[mapi[7]];
    const void* beta_use = d_in[mapi[8]];
    const void* beta_ign = d_in[mapi[9]];
    const int*  iters    = (const int*)d_in[mapi[10]];
    float* out = (float*)d_out;

    // ws layout: [flag 256B][fa: 32*C f32][mu: 32*C*64 f32][V: 32*16*C*64 f32]
    // need(C) = 256 + C*(128 + 8192 + 131072)
    int C = 64;
    {
        const int cands[5] = {1024, 512, 256, 128, 64};
        for (int i = 0; i < 5; i++) {
            size_t need = 256 + (size_t)cands[i] * (128 + 8192 + 131072);
            if (need <= ws_size) { C = cands[i]; break; }
        }
    }

    char* ws = (char*)d_ws;
    int*   flag = (int*)ws;
    float* fa   = (float*)(ws + 256);
    float* mu   = (float*)(ws + 256 + (size_t)128 * C);
    float* V    = (float*)(ws + 256 + (size_t)128 * C + (size_t)8192 * C);

    detect_kernel<<<1, 64, 0, stream>>>(x, flag);

    for (int nbase = 0; nbase < N_DIM; nbase += C) {
        kernelA<<<dim3(C / 64, 32), 256, 0, stream>>>(
            x, mask, Wscore, Bscore, Wcap, Bcap, flag, mu, fa, nbase, C);
        kernelB<<<dim3(C / 64, 16, 32), 256, 0, stream>>>(
            mu, Wvote, Bvote, flag, V, C);
        kernelC<<<dim3(C), 256, 0, stream>>>(
            V, fa, beta_use, beta_ign, iters, flag, out, nbase, C);
    }
}

// Round 7
// 297.408 us; speedup vs baseline: 1.4443x; 1.4443x over previous
//
#include <hip/hip_runtime.h>
#include <hip/hip_bf16.h>

#define L_DIM 32
#define N_DIM 1024
#define D_DIM 768
#define K_DIM 16
#define I_DIM 64
#define O_DIM 64
#define EPSF 1e-8f
#define PX 72   // padded LDS row (bf16 elems): 144 B = 16B-aligned, 2-way banks only

typedef unsigned short u16;
typedef __attribute__((ext_vector_type(8))) short short8;   // 8 bf16 (4 VGPRs)
typedef __attribute__((ext_vector_type(4))) float f32x4;
#define MFMA __builtin_amdgcn_mfma_f32_16x16x32_bf16

__device__ __forceinline__ float bf2f(u16 v) {
    union { unsigned int u; float f; } x; x.u = ((unsigned int)v) << 16; return x.f;
}
__device__ __forceinline__ u16 f2bf(float f) {
    union { float f; unsigned int u; } x; x.f = f;
    unsigned int u = x.u;
    u += 0x7FFFu + ((u >> 16) & 1u);   // RNE
    return (u16)(u >> 16);
}
__device__ __forceinline__ void split2(float v, u16& h, u16& l) {
    u16 hh = f2bf(v);
    h = hh;
    l = f2bf(v - bf2f(hh));
}

// ---------------------------------------------------------------------------
// Prep 1: Wcap [l][d][i] f32  ->  ws [l][i][d] bf16 hi/lo.  grid (12, 32).
// ---------------------------------------------------------------------------
__global__ __launch_bounds__(256) void prep_wcap(
    const float* __restrict__ W, u16* __restrict__ H, u16* __restrict__ Lo)
{
    const int l = blockIdx.y, d0 = blockIdx.x * 64, t = threadIdx.x;
    __shared__ float tile[64][65];
    #pragma unroll
    for (int p = 0; p < 4; p++) {
        int dd = p * 16 + (t >> 4), i4 = (t & 15) * 4;
        float4 v = *(const float4*)&W[((size_t)l * D_DIM + d0 + dd) * I_DIM + i4];
        tile[dd][i4] = v.x; tile[dd][i4+1] = v.y; tile[dd][i4+2] = v.z; tile[dd][i4+3] = v.w;
    }
    __syncthreads();
    #pragma unroll
    for (int p = 0; p < 4; p++) {
        int i = p * 16 + (t >> 4), dd0 = (t & 15) * 4;
        u16 h[4], lo[4];
        #pragma unroll
        for (int j = 0; j < 4; j++) split2(tile[dd0 + j][i], h[j], lo[j]);
        size_t base = ((size_t)l * I_DIM + i) * D_DIM + d0 + dd0;
        uint2 ph; ph.x = h[0] | ((unsigned)h[1] << 16); ph.y = h[2] | ((unsigned)h[3] << 16);
        uint2 pl; pl.x = lo[0] | ((unsigned)lo[1] << 16); pl.y = lo[2] | ((unsigned)lo[3] << 16);
        *(uint2*)&H[base] = ph;
        *(uint2*)&Lo[base] = pl;
    }
}

// ---------------------------------------------------------------------------
// Prep 2: Wvote [l][k][i][o] f32 -> ws [l][k][o][i] bf16 hi/lo. grid (16, 32).
// ---------------------------------------------------------------------------
__global__ __launch_bounds__(256) void prep_wvote(
    const float* __restrict__ W, u16* __restrict__ H, u16* __restrict__ Lo)
{
    const int l = blockIdx.y, k = blockIdx.x, t = threadIdx.x;
    __shared__ float tile[64][65];
    #pragma unroll
    for (int p = 0; p < 4; p++) {
        int i = p * 16 + (t >> 4), o4 = (t & 15) * 4;
        float4 v = *(const float4*)&W[(((size_t)l * K_DIM + k) * I_DIM + i) * O_DIM + o4];
        tile[i][o4] = v.x; tile[i][o4+1] = v.y; tile[i][o4+2] = v.z; tile[i][o4+3] = v.w;
    }
    __syncthreads();
    #pragma unroll
    for (int p = 0; p < 4; p++) {
        int o = p * 16 + (t >> 4), i0 = (t & 15) * 4;
        u16 h[4], lo[4];
        #pragma unroll
        for (int j = 0; j < 4; j++) split2(tile[i0 + j][o], h[j], lo[j]);
        size_t base = (((size_t)l * K_DIM + k) * O_DIM + o) * I_DIM + i0;
        uint2 ph; ph.x = h[0] | ((unsigned)h[1] << 16); ph.y = h[2] | ((unsigned)h[3] << 16);
        uint2 pl; pl.x = lo[0] | ((unsigned)lo[1] << 16); pl.y = lo[2] | ((unsigned)lo[3] << 16);
        *(uint2*)&H[base] = ph;
        *(uint2*)&Lo[base] = pl;
    }
}

// ---------------------------------------------------------------------------
// Kernel A (MFMA): mu[l,nl,i] = gelu(x·Wcap + Bcap); fa = sigmoid(x·Wscore+Bs)·mask
// grid (nchunk/32, 32), block 256 (4 waves). Wave w owns i-tile w; 2 n-tiles.
// hi/lo split: 3 MFMAs per tile pair. A-frag = Wcap[l][i][d] (global, pre-split),
// B-frag = x rows in LDS [n][k] bf16 hi/lo.
// ---------------------------------------------------------------------------
__global__ __launch_bounds__(256) void kernelA(
    const float* __restrict__ x, const float* __restrict__ mask,
    const float* __restrict__ Wscore, const float* __restrict__ Bscore,
    const u16* __restrict__ WcH, const u16* __restrict__ WcL,
    const float* __restrict__ Bcap,
    float* __restrict__ mu_out, float* __restrict__ fa_out,
    int nbase, int nchunk)
{
    const int l   = blockIdx.y;
    const int n0l = blockIdx.x * 32;
    const int t    = threadIdx.x;
    const int w    = t >> 6;
    const int lane = t & 63;
    const int quad = lane >> 4;
    const int ln16 = lane & 15;

    __shared__ u16 xh[32][PX], xl[32][PX];
    __shared__ float wsc_s[64];
    __shared__ float bcap_s[64];

    if (t < 64) bcap_s[t] = Bcap[l * I_DIM + t];

    f32x4 acc[2] = {{0.f,0.f,0.f,0.f},{0.f,0.f,0.f,0.f}};
    float apart = 0.f;

    for (int ch = 0; ch < 12; ch++) {
        const int k0 = ch * 64;
        __syncthreads();
        // stage x chunk: 32 n x 64 d, split hi/lo
        #pragma unroll
        for (int p = 0; p < 2; p++) {
            int n = p * 16 + (t >> 4), d0 = (t & 15) * 4;
            float4 v = *(const float4*)&x[((size_t)(nbase + n0l + n) * L_DIM + l) * D_DIM + k0 + d0];
            u16 h[4], lo[4];
            split2(v.x, h[0], lo[0]); split2(v.y, h[1], lo[1]);
            split2(v.z, h[2], lo[2]); split2(v.w, h[3], lo[3]);
            uint2 ph; ph.x = h[0] | ((unsigned)h[1] << 16); ph.y = h[2] | ((unsigned)h[3] << 16);
            uint2 pl; pl.x = lo[0] | ((unsigned)lo[1] << 16); pl.y = lo[2] | ((unsigned)lo[3] << 16);
            *(uint2*)&xh[n][d0] = ph;
            *(uint2*)&xl[n][d0] = pl;
        }
        if (t < 64) wsc_s[t] = Wscore[l * D_DIM + k0 + t];
        __syncthreads();

        // fa partial: thread handles n = t>>3, dd-slice (t&7)*8..+8
        {
            const int n = t >> 3, s8 = (t & 7) * 8;
            float ss = 0.f;
            #pragma unroll
            for (int j = 0; j < 8; j++) {
                int dd = s8 + j;
                ss += (bf2f(xh[n][dd]) + bf2f(xl[n][dd])) * wsc_s[dd];
            }
            apart += ss;
        }

        // MFMA over two k-steps of 32
        #pragma unroll
        for (int ks = 0; ks < 2; ks++) {
            const int kk = ks * 32;
            size_t wbase = ((size_t)l * I_DIM + (w * 16 + ln16)) * D_DIM + k0 + kk + quad * 8;
            short8 ah = *(const short8*)&WcH[wbase];
            short8 al = *(const short8*)&WcL[wbase];
            #pragma unroll
            for (int c = 0; c < 2; c++) {
                const int n = c * 16 + ln16;
                short8 bh = *(const short8*)&xh[n][kk + quad * 8];
                short8 bl = *(const short8*)&xl[n][kk + quad * 8];
                acc[c] = MFMA(ah, bh, acc[c], 0, 0, 0);
                acc[c] = MFMA(ah, bl, acc[c], 0, 0, 0);
                acc[c] = MFMA(al, bh, acc[c], 0, 0, 0);
            }
        }
    }

    // fa: reduce 8 sub-lanes (consecutive lanes within wave)
    apart += __shfl_xor(apart, 1, 64);
    apart += __shfl_xor(apart, 2, 64);
    apart += __shfl_xor(apart, 4, 64);
    if ((t & 7) == 0) {
        int n = t >> 3;
        float a = apart + Bscore[l];
        float sig = 1.f / (1.f + expf(-a));
        float m = mask[(size_t)(nbase + n0l + n) * L_DIM + l];
        fa_out[(size_t)l * nchunk + n0l + n] = sig * m;
    }

    // mu epilogue: D row = i = w*16 + quad*4 + r; col n = c*16 + ln16
    #pragma unroll
    for (int c = 0; c < 2; c++) {
        const int n = c * 16 + ln16;
        const int i0 = w * 16 + quad * 4;
        float4 o;
        float* op = (float*)&o;
        #pragma unroll
        for (int r = 0; r < 4; r++) {
            float v = acc[c][r] + bcap_s[i0 + r];
            op[r] = 0.5f * v * (1.f + erff(v * 0.70710678118f));
        }
        *(float4*)&mu_out[((size_t)l * nchunk + n0l + n) * I_DIM + i0] = o;
    }
}

// ---------------------------------------------------------------------------
// Kernel B (MFMA): V[l,k,nl,o] = mu·Wvote + Bvote (f32). grid (nchunk/64,16,32).
// Wave w owns o-tile w; 4 n-tiles. K=64 (i), 2 k-steps.
// ---------------------------------------------------------------------------
__global__ __launch_bounds__(256) void kernelB(
    const float* __restrict__ mu_in,
    const u16* __restrict__ WvH, const u16* __restrict__ WvL,
    const float* __restrict__ Bvote,
    float* __restrict__ V, int nchunk)
{
    const int l   = blockIdx.z;
    const int k   = blockIdx.y;
    const int n0l = blockIdx.x * 64;
    const int t    = threadIdx.x;
    const int w    = t >> 6;
    const int lane = t & 63;
    const int quad = lane >> 4;
    const int ln16 = lane & 15;

    __shared__ u16 mh[64][PX], ml[64][PX];
    __shared__ float bvote_s[64];

    if (t < 64) bvote_s[t] = Bvote[((size_t)l * K_DIM + k) * O_DIM + t];

    #pragma unroll
    for (int p = 0; p < 4; p++) {
        int n = p * 16 + (t >> 4), i0 = (t & 15) * 4;
        float4 v = *(const float4*)&mu_in[((size_t)l * nchunk + n0l + n) * I_DIM + i0];
        u16 h[4], lo[4];
        split2(v.x, h[0], lo[0]); split2(v.y, h[1], lo[1]);
        split2(v.z, h[2], lo[2]); split2(v.w, h[3], lo[3]);
        uint2 ph; ph.x = h[0] | ((unsigned)h[1] << 16); ph.y = h[2] | ((unsigned)h[3] << 16);
        uint2 pl; pl.x = lo[0] | ((unsigned)lo[1] << 16); pl.y = lo[2] | ((unsigned)lo[3] << 16);
        *(uint2*)&mh[n][i0] = ph;
        *(uint2*)&ml[n][i0] = pl;
    }
    __syncthreads();

    f32x4 acc[4] = {{0.f,0.f,0.f,0.f},{0.f,0.f,0.f,0.f},{0.f,0.f,0.f,0.f},{0.f,0.f,0.f,0.f}};

    #pragma unroll
    for (int ks = 0; ks < 2; ks++) {
        const int kk = ks * 32;
        size_t wbase = (((size_t)l * K_DIM + k) * O_DIM + (w * 16 + ln16)) * I_DIM + kk + quad * 8;
        short8 ah = *(const short8*)&WvH[wbase];
        short8 al = *(const short8*)&WvL[wbase];
        #pragma unroll
        for (int c = 0; c < 4; c++) {
            const int n = c * 16 + ln16;
            short8 bh = *(const short8*)&mh[n][kk + quad * 8];
            short8 bl = *(const short8*)&ml[n][kk + quad * 8];
            acc[c] = MFMA(ah, bh, acc[c], 0, 0, 0);
            acc[c] = MFMA(ah, bl, acc[c], 0, 0, 0);
            acc[c] = MFMA(al, bh, acc[c], 0, 0, 0);
        }
    }

    // D row = o = w*16 + quad*4 + r; col n = c*16 + ln16
    #pragma unroll
    for (int c = 0; c < 4; c++) {
        const int n = c * 16 + ln16;
        const int o0 = w * 16 + quad * 4;
        float4 o;
        o.x = acc[c][0] + bvote_s[o0];
        o.y = acc[c][1] + bvote_s[o0 + 1];
        o.z = acc[c][2] + bvote_s[o0 + 2];
        o.w = acc[c][3] + bvote_s[o0 + 3];
        *(float4*)&V[(((size_t)l * K_DIM + k) * nchunk + n0l + n) * O_DIM + o0] = o;
    }
}

// ---------------------------------------------------------------------------
// Kernel C: EM routing (unchanged from the passing round-6 version).
// ---------------------------------------------------------------------------
__global__ __launch_bounds__(256) void kernelC(
    const float* __restrict__ V, const float* __restrict__ fa_in,
    const float* __restrict__ beta_use, const float* __restrict__ beta_ign,
    const int* __restrict__ iters_p,
    float* __restrict__ out, int nbase, int nchunk)
{
    const int nl = blockIdx.x;
    const int ng = nbase + nl;
    const int t  = threadIdx.x;
    const int k  = t >> 4;
    const int og = (t & 15) << 2;
    int iters = iters_p[0];
    if (iters < 0 || iters > 16) iters = 3;

    __shared__ float fa_s[32];
    __shared__ float bu_s[32];
    __shared__ float R_s[32][17];
    __shared__ float sc_s[32][17];

    if (t < 32) {
        fa_s[t] = fa_in[(size_t)t * nchunk + nl];
        bu_s[t] = beta_use[t];
    }
    for (int idx = t; idx < 512; idx += 256)
        R_s[idx >> 4][idx & 15] = 1.f / 16.f;
    const float bi_k = beta_ign[k];

    float Vr[32][4];
    #pragma unroll
    for (int l = 0; l < 32; l++) {
        float4 v = *(const float4*)&V[(((size_t)l * K_DIM + k) * nchunk + nl) * O_DIM + og];
        Vr[l][0] = v.x; Vr[l][1] = v.y; Vr[l][2] = v.z; Vr[l][3] = v.w;
    }
    __syncthreads();

    float mu_r[4] = {0.f, 0.f, 0.f, 0.f};
    float var_r[4] = {0.f, 0.f, 0.f, 0.f};
    float a_r = 0.f;

    for (int it = 0; it < iters; it++) {
        if (it > 0) {
            float inv2v[4], lvp = 0.f;
            #pragma unroll
            for (int j = 0; j < 4; j++) {
                inv2v[j] = 1.f / (2.f * var_r[j] + EPSF);
                lvp += logf(var_r[j] + EPSF);
            }
            lvp += __shfl_xor(lvp, 1, 64);
            lvp += __shfl_xor(lvp, 2, 64);
            lvp += __shfl_xor(lvp, 4, 64);
            lvp += __shfl_xor(lvp, 8, 64);
            float ls = fminf(a_r, 0.f) - log1pf(expf(-fabsf(a_r)));
            const float cst = ls - 1.f - 1.57079632679f - 0.5f * lvp;
            #pragma unroll
            for (int l = 0; l < 32; l++) {
                float s = 0.f;
                #pragma unroll
                for (int j = 0; j < 4; j++) {
                    float d = Vr[l][j] - mu_r[j];
                    s += d * d * inv2v[j];
                }
                s = -s;
                s += __shfl_xor(s, 1, 64);
                s += __shfl_xor(s, 2, 64);
                s += __shfl_xor(s, 4, 64);
                s += __shfl_xor(s, 8, 64);
                if ((t & 15) == 0) sc_s[l][k] = s + cst;
            }
            __syncthreads();
            if (t < 32) {
                const int l = t;
                float m = -3.4e38f;
                #pragma unroll
                for (int kk = 0; kk < 16; kk++) m = fmaxf(m, sc_s[l][kk]);
                float e[16]; float sum = 0.f;
                #pragma unroll
                for (int kk = 0; kk < 16; kk++) { e[kk] = expf(sc_s[l][kk] - m); sum += e[kk]; }
                float inv = 1.f / sum;
                #pragma unroll
                for (int kk = 0; kk < 16; kk++) R_s[l][kk] = e[kk] * inv;
            }
            __syncthreads();
        }
        float denom = EPSF, a_acc = 0.f;
        float mu_a[4] = {0.f, 0.f, 0.f, 0.f};
        #pragma unroll
        for (int l = 0; l < 32; l++) {
            float Du = fa_s[l] * R_s[l][k];
            denom += Du;
            #pragma unroll
            for (int j = 0; j < 4; j++) mu_a[j] += Du * Vr[l][j];
            a_acc += bu_s[l] * Du - bi_k * (fa_s[l] - Du);
        }
        float invd = 1.f / denom;
        #pragma unroll
        for (int j = 0; j < 4; j++) mu_r[j] = mu_a[j] * invd;
        a_r = a_acc;
        float var_a[4] = {0.f, 0.f, 0.f, 0.f};
        #pragma unroll
        for (int l = 0; l < 32; l++) {
            float Du = fa_s[l] * R_s[l][k];
            #pragma unroll
            for (int j = 0; j < 4; j++) {
                float d = Vr[l][j] - mu_r[j];
                var_a[j] += Du * d * d;
            }
        }
        #pragma unroll
        for (int j = 0; j < 4; j++) var_r[j] = var_a[j] * invd;
    }

    if ((t & 15) == 0) out[(size_t)ng * K_DIM + k] = a_r;
    float4 o4;
    o4.x = mu_r[0]; o4.y = mu_r[1]; o4.z = mu_r[2]; o4.w = mu_r[3];
    *(float4*)&out[(size_t)N_DIM * K_DIM + ((size_t)ng * K_DIM + k) * O_DIM + og] = o4;
}

extern "C" void kernel_launch(void* const* d_in, const int* in_sizes, int n_in,
                              void* d_out, int out_size, void* d_ws, size_t ws_size,
                              hipStream_t stream) {
    (void)out_size;
    static const int EXP[11] = {25165824, 32768, 24576, 32, 1572864, 64,
                                2097152, 65536, 32, 16, 1};
    int mapi[11];
    bool used[64] = {false};
    for (int s = 0; s < 11; s++) {
        mapi[s] = (s < n_in) ? s : 0;
        for (int j = 0; j < n_in && j < 64; j++) {
            if (!used[j] && in_sizes[j] == EXP[s]) { mapi[s] = j; used[j] = true; break; }
        }
    }
    const float* x        = (const float*)d_in[mapi[0]];
    const float* mask     = (const float*)d_in[mapi[1]];
    const float* Wscore   = (const float*)d_in[mapi[2]];
    const float* Bscore   = (const float*)d_in[mapi[3]];
    const float* Wcap     = (const float*)d_in[mapi[4]];
    const float* Bcap     = (const float*)d_in[mapi[5]];
    const float* Wvote    = (const float*)d_in[mapi[6]];
    const float* Bvote    = (const float*)d_in[mapi[7]];
    const float* beta_use = (const float*)d_in[mapi[8]];
    const float* beta_ign = (const float*)d_in[mapi[9]];
    const int*   iters    = (const int*)d_in[mapi[10]];
    float* out = (float*)d_out;

    // ws: [WcapH 3M][WcapL 3M][WvoteH 4M][WvoteL 4M][fa 128C][mu 8192C][V 131072C]
    const size_t WCAP = (size_t)L_DIM * I_DIM * D_DIM;       // u16 elems (1.5M)
    const size_t WVOT = (size_t)L_DIM * K_DIM * O_DIM * I_DIM; // u16 elems (2M)
    const size_t WBYTES = 2 * WCAP * 2 + 2 * WVOT * 2;       // 14,680,064 B

    int C = 64;
    {
        const int cands[5] = {1024, 512, 256, 128, 64};
        for (int i = 0; i < 5; i++) {
            size_t need = WBYTES + (size_t)cands[i] * (128 + 8192 + 131072);
            if (need <= ws_size) { C = cands[i]; break; }
        }
    }

    char* ws = (char*)d_ws;
    u16* WcH = (u16*)ws;
    u16* WcL = (u16*)(ws + WCAP * 2);
    u16* WvH = (u16*)(ws + WCAP * 4);
    u16* WvL = (u16*)(ws + WCAP * 4 + WVOT * 2);
    char* dyn = ws + WBYTES;
    float* fa = (float*)dyn;
    float* mu = (float*)(dyn + (size_t)128 * C);
    float* V  = (float*)(dyn + (size_t)128 * C + (size_t)8192 * C);

    prep_wcap<<<dim3(12, 32), 256, 0, stream>>>(Wcap, WcH, WcL);
    prep_wvote<<<dim3(16, 32), 256, 0, stream>>>(Wvote, WvH, WvL);

    for (int nbase = 0; nbase < N_DIM; nbase += C) {
        kernelA<<<dim3(C / 32, 32), 256, 0, stream>>>(
            x, mask, Wscore, Bscore, WcH, WcL, Bcap, mu, fa, nbase, C);
        kernelB<<<dim3(C / 64, 16, 32), 256, 0, stream>>>(
            mu, WvH, WvL, Bvote, V, C);
        kernelC<<<dim3(C), 256, 0, stream>>>(
            V, fa, beta_use, beta_ign, iters, out, nbase, C);
    }
}